// Round 8
// baseline (177.657 us; speedup 1.0000x reference)
//
#include <hip/hip_runtime.h>
#include <hip/hip_cooperative_groups.h>
#include <math.h>

#define A_TOT   18675      // 83*25*9
#define N_PRE   12000
#define N_POST  2000
#define IMG_X   1333.0f
#define IMG_Y   402.0f
#define MIN_SZ  16.0f
#define NMS_T   0.7f
#define NBUCK   4096       // top 12 bits of descending-order key
#define GBLK    256
#define NTHR    1024
#define NWAVES  (GBLK * (NTHR / 64))   // 4096 waves

namespace cg = cooperative_groups;

__global__ __launch_bounds__(NTHR)
void fused_kernel(const float* __restrict__ anch,
                  const float* __restrict__ cls,
                  const float* __restrict__ pred,
                  float4* __restrict__ roi,
                  unsigned long long* __restrict__ key,
                  unsigned* __restrict__ ghist,
                  unsigned* __restrict__ gcnt,
                  unsigned long long* __restrict__ bkey,
                  float4* __restrict__ sboxes,
                  float* __restrict__ sareas,
                  unsigned* __restrict__ mark,
                  float* __restrict__ out)
{
    cg::grid_group grid = cg::this_grid();

    __shared__ unsigned bs[NBUCK];     // bucket start (exclusive prefix)
    __shared__ unsigned lcnt[NBUCK];   // bucket count
    __shared__ unsigned wsum[16];
    __shared__ int wsA[16], wsB[16], wsS[16];
    __shared__ int s_base, s_total;

    const int t    = threadIdx.x;
    const int blk  = blockIdx.x;
    const int g    = blk * NTHR + t;
    const int lane = t & 63;
    const int wv   = t >> 6;
    const int gw   = blk * (NTHR / 64) + wv;   // global wave id

    // ---------- phase 0: zero global hist + scatter cursors ----------
    if (g < NBUCK) { ghist[g] = 0u; gcnt[g] = 0u; }
    grid.sync();

    // ---------- phase 1: decode -> roi, key64; global histogram ----------
    if (g < A_TOT) {
        float ax1 = anch[4*g+0], ay1 = anch[4*g+1], ax2 = anch[4*g+2], ay2 = anch[4*g+3];
        float h_a  = __fsub_rn(ay2, ay1);
        float w_a  = __fsub_rn(ax2, ax1);
        float cy_a = __fadd_rn(ay1, __fmul_rn(0.5f, h_a));
        float cx_a = __fadd_rn(ax1, __fmul_rn(0.5f, w_a));

        float dx = pred[4*g+0], dy = pred[4*g+1], dw = pred[4*g+2], dh = pred[4*g+3];

        float cy = __fadd_rn(__fmul_rn(dy, h_a), cy_a);
        float cx = __fadd_rn(__fmul_rn(dx, w_a), cx_a);
        float h  = __fmul_rn(expf(dh), h_a);
        float w  = __fmul_rn(expf(dw), w_a);

        float hw = __fmul_rn(0.5f, w);
        float hh = __fmul_rn(0.5f, h);
        float x1 = fminf(fmaxf(__fsub_rn(cx, hw), 0.0f), IMG_X);
        float x2 = fminf(fmaxf(__fadd_rn(cx, hw), 0.0f), IMG_X);
        float y1 = fminf(fmaxf(__fsub_rn(cy, hh), 0.0f), IMG_Y);
        float y2 = fminf(fmaxf(__fadd_rn(cy, hh), 0.0f), IMG_Y);

        bool valid = (__fsub_rn(y2, y1) >= MIN_SZ) && (__fsub_rn(x2, x1) >= MIN_SZ);

        roi[g] = make_float4(x1, y1, x2, y2);

        float s = valid ? cls[2*g+1] : -INFINITY;
        unsigned ub   = __float_as_uint(s);
        unsigned mask = ((unsigned)((int)ub >> 31)) | 0x80000000u;
        unsigned ord  = ub ^ mask;          // ascending float order
        unsigned kd   = ~ord;               // descending float order
        key[g] = ((unsigned long long)kd << 32) | (unsigned)g;
        atomicAdd(&ghist[kd >> 20], 1u);
    }
    grid.sync();

    // ---------- phase 2: redundant per-block exclusive scan -> LDS ----------
    {
        uint4 v = ((const uint4*)ghist)[t];
        unsigned c0 = v.x, c1 = v.y, c2 = v.z, c3 = v.w;
        unsigned mysum = c0 + c1 + c2 + c3;
        unsigned incl = mysum;
#pragma unroll
        for (int off = 1; off < 64; off <<= 1) {
            unsigned x = __shfl_up(incl, off, 64);
            if (lane >= off) incl += x;
        }
        if (lane == 63) wsum[wv] = incl;
        __syncthreads();
        if (t == 0) {
            unsigned run = 0;
            for (int k = 0; k < 16; ++k) { unsigned x = wsum[k]; wsum[k] = run; run += x; }
        }
        __syncthreads();
        unsigned base = wsum[wv] + (incl - mysum);
        bs[4*t+0] = base;
        bs[4*t+1] = base + c0;
        bs[4*t+2] = base + c0 + c1;
        bs[4*t+3] = base + c0 + c1 + c2;
        lcnt[4*t+0] = c0; lcnt[4*t+1] = c1; lcnt[4*t+2] = c2; lcnt[4*t+3] = c3;
        __syncthreads();
    }

    // ---------- phase 3: bucket scatter ----------
    if (g < A_TOT) {
        unsigned long long Ki = key[g];
        unsigned b = (unsigned)(Ki >> 52);
        unsigned pos = bs[b] + atomicAdd(&gcnt[b], 1u);
        bkey[pos] = Ki;
    }
    grid.sync();

    // ---------- phase 4: wave-ballot exact rank + scatter ----------
    for (int p = gw; p < A_TOT; p += NWAVES) {
        unsigned long long Ki = bkey[p];
        unsigned b = (unsigned)(Ki >> 52);
        unsigned start = bs[b];
        if (start >= N_PRE) continue;      // whole bucket past top-N_PRE
        unsigned cnt = lcnt[b];
        unsigned r = start;
        for (unsigned m = 0; m < cnt; m += 64) {
            unsigned mm = m + lane;
            bool lt = (mm < cnt) && (bkey[start + mm] < Ki);
            r += (unsigned)__popcll(__ballot(lt));
        }
        if (lane == 0 && r < N_PRE) {
            unsigned idx = (unsigned)Ki;
            float4 bx = roi[idx];
            sboxes[r] = bx;
            sareas[r] = __fmul_rn(__fadd_rn(__fsub_rn(bx.z, bx.x), 1.0f),
                                  __fadd_rn(__fsub_rn(bx.w, bx.y), 1.0f));
        }
    }
    grid.sync();

    // ---------- phase 5: diagonal pair-overlap marking ----------
    for (int i = gw; i < N_PRE; i += NWAVES) {
        const int npairs = N_PRE - 1 - i;
        bool found = false;
        for (int base0 = 0; base0 < npairs; base0 += 64) {
            int z = base0 + lane;
            bool over = false;
            if (z < npairs) {
                float4 bz = sboxes[z];
                float4 bj = sboxes[z + i + 1];
                float az = sareas[z];
                float aj = sareas[z + i + 1];
                float xx1 = fmaxf(bz.x, bj.x);
                float yy1 = fmaxf(bz.y, bj.y);
                float xx2 = fminf(bz.z, bj.z);
                float yy2 = fminf(bz.w, bj.w);
                float w = fmaxf(0.0f, __fadd_rn(__fsub_rn(xx2, xx1), 1.0f));
                float h = fmaxf(0.0f, __fadd_rn(__fsub_rn(yy2, yy1), 1.0f));
                float inter = __fmul_rn(w, h);
                float denom = __fsub_rn(__fadd_rn(az, aj), inter);
                float ovr   = __fdiv_rn(inter, denom);
                over = (ovr >= NMS_T);
            }
            if (__any(over)) { found = true; break; }
        }
        if (lane == 0) mark[i] = found ? 1u : 0u;
    }
    grid.sync();

    // ---------- phase 6: compaction + output (blocks 0..11) ----------
    if (blk < 12) {
        const int limit = blk * NTHR;

        int sum_before = 0, sum_total = 0;
        for (int j = t; j < N_PRE; j += NTHR) {
            int k = (mark[j] == 0u) ? 1 : 0;
            sum_total += k;
            if (j < limit) sum_before += k;
        }
#pragma unroll
        for (int off = 32; off > 0; off >>= 1) {
            sum_before += __shfl_xor(sum_before, off, 64);
            sum_total  += __shfl_xor(sum_total,  off, 64);
        }
        if (lane == 0) { wsA[wv] = sum_before; wsB[wv] = sum_total; }
        __syncthreads();
        if (t == 0) {
            int a = 0, b = 0;
            for (int k = 0; k < 16; ++k) { a += wsA[k]; b += wsB[k]; }
            s_base = a; s_total = b;
        }
        __syncthreads();

        const int i = blk * NTHR + t;
        int keep = (i < N_PRE) && (mark[i] == 0u);

        int incl = keep;
#pragma unroll
        for (int off = 1; off < 64; off <<= 1) {
            int x = __shfl_up(incl, off, 64);
            if (lane >= off) incl += x;
        }
        if (lane == 63) wsS[wv] = incl;
        __syncthreads();
        if (t == 0) {
            int run = 0;
            for (int k = 0; k < 16; ++k) { int x = wsS[k]; wsS[k] = run; run += x; }
        }
        __syncthreads();

        int pos = s_base + wsS[wv] + (incl - keep);
        if (keep && pos < N_POST) {
            float4 b4 = sboxes[i];
            out[4*pos+0] = b4.x;
            out[4*pos+1] = b4.y;
            out[4*pos+2] = b4.z;
            out[4*pos+3] = b4.w;
            out[4*N_POST + pos] = 1.0f;
        }
        if (i < N_POST && i >= s_total) {
            out[4*i+0] = 0.0f; out[4*i+1] = 0.0f;
            out[4*i+2] = 0.0f; out[4*i+3] = 0.0f;
            out[4*N_POST + i] = 0.0f;
        }
    }
}

// ---------------- launch ------------------------------------------------------
extern "C" void kernel_launch(void* const* d_in, const int* in_sizes, int n_in,
                              void* d_out, int out_size, void* d_ws, size_t ws_size,
                              hipStream_t stream) {
    const float* anch = (const float*)d_in[0];   // (A,4)
    const float* cls  = (const float*)d_in[1];   // (1,A,2)
    const float* pred = (const float*)d_in[2];   // (1,A,4)
    float* out = (float*)d_out;                  // 8000 rois + 2000 kept

    char* ws = (char*)d_ws;
    float4*             roi    = (float4*)(ws + 0);                   // 298,800
    unsigned long long* key    = (unsigned long long*)(ws + 299008);  // 149,400
    unsigned*           ghist  = (unsigned*)(ws + 448512);            //  16,384
    unsigned*           gcnt   = (unsigned*)(ws + 464896);            //  16,384
    unsigned long long* bkey   = (unsigned long long*)(ws + 481280);  // 149,400
    float4*             sboxes = (float4*)(ws + 630784);              // 192,000
    float*              sareas = (float*)(ws + 822784);               //  48,000
    unsigned*           mark   = (unsigned*)(ws + 870784);            //  48,000

    void* args[] = {
        (void*)&anch, (void*)&cls, (void*)&pred,
        (void*)&roi, (void*)&key, (void*)&ghist, (void*)&gcnt,
        (void*)&bkey, (void*)&sboxes, (void*)&sareas, (void*)&mark, (void*)&out
    };
    hipLaunchCooperativeKernel((const void*)fused_kernel,
                               dim3(GBLK), dim3(NTHR), args, 0, stream);
}

// Round 9
// 103.229 us; speedup vs baseline: 1.7210x; 1.7210x over previous
//
#include <hip/hip_runtime.h>
#include <math.h>

#define A_TOT   18675      // 83*25*9
#define N_PRE   12000
#define N_POST  2000
#define IMG_X   1333.0f
#define IMG_Y   402.0f
#define MIN_SZ  16.0f
#define NMS_T   0.7f
#define NBUCK   4096       // top 12 bits of descending-order key
#define NB0     19         // decode blocks (19*1024 >= A_TOT)
#define NB1     64         // main kernel blocks
#define NW1     (NB1*16)   // main kernel waves (1024)

// ---------------- D0: init + decode -> roi, key, partial hists ---------------
__global__ __launch_bounds__(1024)
void decode_kernel(const float* __restrict__ anch,
                   const float* __restrict__ cls,
                   const float* __restrict__ pred,
                   float4* __restrict__ roi,
                   unsigned long long* __restrict__ key,
                   unsigned* __restrict__ phist,
                   unsigned* __restrict__ gcnt,
                   unsigned* __restrict__ sync) {
    __shared__ unsigned lh[NBUCK];
    const int t   = threadIdx.x;
    const int blk = blockIdx.x;
    const int g   = blk * 1024 + t;

#pragma unroll
    for (int e = 0; e < 4; ++e) lh[t + e * 1024] = 0u;
    if (g < NBUCK) gcnt[g] = 0u;
    if (g == NBUCK) { sync[0] = 0u; sync[32] = 0u; }   // bar, done
    __syncthreads();

    if (g < A_TOT) {
        float ax1 = anch[4*g+0], ay1 = anch[4*g+1], ax2 = anch[4*g+2], ay2 = anch[4*g+3];
        float h_a  = __fsub_rn(ay2, ay1);
        float w_a  = __fsub_rn(ax2, ax1);
        float cy_a = __fadd_rn(ay1, __fmul_rn(0.5f, h_a));
        float cx_a = __fadd_rn(ax1, __fmul_rn(0.5f, w_a));

        float dx = pred[4*g+0], dy = pred[4*g+1], dw = pred[4*g+2], dh = pred[4*g+3];

        float cy = __fadd_rn(__fmul_rn(dy, h_a), cy_a);
        float cx = __fadd_rn(__fmul_rn(dx, w_a), cx_a);
        float h  = __fmul_rn(expf(dh), h_a);
        float w  = __fmul_rn(expf(dw), w_a);

        float hw = __fmul_rn(0.5f, w);
        float hh = __fmul_rn(0.5f, h);
        float x1 = fminf(fmaxf(__fsub_rn(cx, hw), 0.0f), IMG_X);
        float x2 = fminf(fmaxf(__fadd_rn(cx, hw), 0.0f), IMG_X);
        float y1 = fminf(fmaxf(__fsub_rn(cy, hh), 0.0f), IMG_Y);
        float y2 = fminf(fmaxf(__fadd_rn(cy, hh), 0.0f), IMG_Y);

        bool valid = (__fsub_rn(y2, y1) >= MIN_SZ) && (__fsub_rn(x2, x1) >= MIN_SZ);

        roi[g] = make_float4(x1, y1, x2, y2);

        float s = valid ? cls[2*g+1] : -INFINITY;
        unsigned ub   = __float_as_uint(s);
        unsigned mask = ((unsigned)((int)ub >> 31)) | 0x80000000u;
        unsigned ord  = ub ^ mask;          // ascending float order
        unsigned kd   = ~ord;               // descending float order
        key[g] = ((unsigned long long)kd << 32) | (unsigned)g;
        atomicAdd(&lh[kd >> 20], 1u);
    }
    __syncthreads();

    ((uint4*)phist)[blk * 1024 + t] =
        make_uint4(lh[4*t+0], lh[4*t+1], lh[4*t+2], lh[4*t+3]);
}

// ---------------- hand-rolled grid barrier (device-scope) --------------------
__device__ __forceinline__ void gbar(unsigned* bar, unsigned target) {
    __syncthreads();
    if (threadIdx.x == 0) {
        __threadfence();                 // release prior writes to device scope
        atomicAdd(bar, 1u);
        long guard = 0;
        while (atomicAdd(bar, 0u) < target) {
            __builtin_amdgcn_s_sleep(8);
            if (++guard > (1L << 27)) break;   // hang guard only
        }
        __threadfence();                 // acquire
    }
    __syncthreads();
}

// ---------------- D1: scan+scatter | rank | nms | last-block output ----------
__global__ __launch_bounds__(1024)
void main_kernel(const unsigned long long* __restrict__ key,
                 const unsigned* __restrict__ phist,
                 unsigned* __restrict__ gcnt,
                 unsigned long long* __restrict__ bkey,
                 const float4* __restrict__ roi,
                 float4* __restrict__ sboxes,
                 float* __restrict__ sareas,
                 unsigned* __restrict__ mark,
                 unsigned* __restrict__ sync,
                 float* __restrict__ out) {
    __shared__ unsigned bs[NBUCK];
    __shared__ unsigned lcnt[NBUCK];
    __shared__ unsigned wsum[16];
    __shared__ int osum[16];
    __shared__ int ototal;
    __shared__ int sflag;

    const int t    = threadIdx.x;
    const int blk  = blockIdx.x;
    const int lane = t & 63;
    const int wv   = t >> 6;
    const int gw   = blk * 16 + wv;

    // ----- phase A: redundant per-block exclusive scan of summed hists -----
    {
        unsigned c0 = 0, c1 = 0, c2 = 0, c3 = 0;
#pragma unroll
        for (int k = 0; k < NB0; ++k) {
            uint4 v = ((const uint4*)phist)[k * 1024 + t];
            c0 += v.x; c1 += v.y; c2 += v.z; c3 += v.w;
        }
        unsigned mysum = c0 + c1 + c2 + c3;
        unsigned incl = mysum;
#pragma unroll
        for (int off = 1; off < 64; off <<= 1) {
            unsigned x = __shfl_up(incl, off, 64);
            if (lane >= off) incl += x;
        }
        if (lane == 63) wsum[wv] = incl;
        __syncthreads();
        if (t == 0) {
            unsigned run = 0;
            for (int k = 0; k < 16; ++k) { unsigned x = wsum[k]; wsum[k] = run; run += x; }
        }
        __syncthreads();
        unsigned base = wsum[wv] + (incl - mysum);
        bs[4*t+0] = base;
        bs[4*t+1] = base + c0;
        bs[4*t+2] = base + c0 + c1;
        bs[4*t+3] = base + c0 + c1 + c2;
        lcnt[4*t+0] = c0; lcnt[4*t+1] = c1; lcnt[4*t+2] = c2; lcnt[4*t+3] = c3;
        __syncthreads();
    }

    // ----- phase B: bucket scatter (blocks 0..18 carry the elements) -----
    {
        int g = blk * 1024 + t;
        if (g < A_TOT) {
            unsigned long long Ki = key[g];
            unsigned b = (unsigned)(Ki >> 52);
            unsigned pos = bs[b] + atomicAdd(&gcnt[b], 1u);
            bkey[pos] = Ki;
        }
    }
    gbar(sync, NB1);

    // ----- phase C: wave-ballot exact rank + scatter to sorted arrays -----
    for (int p = gw; p < A_TOT; p += NW1) {
        unsigned long long Ki = bkey[p];
        unsigned b = (unsigned)(Ki >> 52);
        unsigned start = bs[b];
        if (start >= N_PRE) continue;        // whole bucket past top-N_PRE
        unsigned cnt = lcnt[b];
        unsigned r = start;
        if (cnt > 1) {
            for (unsigned m = 0; m < cnt; m += 64) {
                unsigned mm = m + lane;
                bool lt = (mm < cnt) && (bkey[start + mm] < Ki);
                r += (unsigned)__popcll(__ballot(lt));
            }
        }
        if (lane == 0 && r < N_PRE) {
            unsigned idx = (unsigned)Ki;
            float4 bx = roi[idx];
            sboxes[r] = bx;
            sareas[r] = __fmul_rn(__fadd_rn(__fsub_rn(bx.z, bx.x), 1.0f),
                                  __fadd_rn(__fsub_rn(bx.w, bx.y), 1.0f));
        }
    }
    gbar(sync, 2u * NB1);

    // ----- phase D: diagonal pair-overlap marking -----
    for (int i = gw; i < N_PRE; i += NW1) {
        const int npairs = N_PRE - 1 - i;
        bool found = false;
        for (int base0 = 0; base0 < npairs; base0 += 64) {
            int z = base0 + lane;
            bool over = false;
            if (z < npairs) {
                float4 bz = sboxes[z];
                float4 bj = sboxes[z + i + 1];
                float az = sareas[z];
                float aj = sareas[z + i + 1];
                float xx1 = fmaxf(bz.x, bj.x);
                float yy1 = fmaxf(bz.y, bj.y);
                float xx2 = fminf(bz.z, bj.z);
                float yy2 = fminf(bz.w, bj.w);
                float w = fmaxf(0.0f, __fadd_rn(__fsub_rn(xx2, xx1), 1.0f));
                float h = fmaxf(0.0f, __fadd_rn(__fsub_rn(yy2, yy1), 1.0f));
                float inter = __fmul_rn(w, h);
                float denom = __fsub_rn(__fadd_rn(az, aj), inter);
                float ovr   = __fdiv_rn(inter, denom);
                over = (ovr >= NMS_T);
            }
            if (__any(over)) { found = true; break; }
        }
        if (lane == 0) mark[i] = found ? 1u : 0u;
    }

    // ----- phase E: last block to finish performs the output -----
    __syncthreads();
    if (t == 0) {
        __threadfence();
        unsigned old = atomicAdd(&sync[32], 1u);
        sflag = (old == NB1 - 1) ? 1 : 0;
    }
    __syncthreads();
    if (!sflag) return;
    __threadfence();

    {
        const int E = 12;                 // 1024*12 = 12288 >= 12000
        const int i0 = t * E;
        bool keep[E];
        int cnt = 0;
#pragma unroll
        for (int e = 0; e < E; ++e) {
            int i = i0 + e;
            bool k = (i < N_PRE) && (mark[i] == 0u);
            keep[e] = k;
            cnt += k ? 1 : 0;
        }
        int incl = cnt;
#pragma unroll
        for (int off = 1; off < 64; off <<= 1) {
            int x = __shfl_up(incl, off, 64);
            if (lane >= off) incl += x;
        }
        if (lane == 63) osum[wv] = incl;
        __syncthreads();
        if (t == 0) {
            int run = 0;
            for (int k = 0; k < 16; ++k) { int x = osum[k]; osum[k] = run; run += x; }
            ototal = run;
        }
        __syncthreads();

        int pos = osum[wv] + (incl - cnt);
#pragma unroll
        for (int e = 0; e < E; ++e) {
            if (keep[e] && pos < N_POST) {
                float4 b4 = sboxes[i0 + e];
                out[4*pos+0] = b4.x;
                out[4*pos+1] = b4.y;
                out[4*pos+2] = b4.z;
                out[4*pos+3] = b4.w;
                out[4*N_POST + pos] = 1.0f;
            }
            pos += keep[e] ? 1 : 0;
        }
        const int total = ototal;
        for (int p = t; p < N_POST; p += 1024) {
            if (p >= total) {
                out[4*p+0] = 0.0f; out[4*p+1] = 0.0f;
                out[4*p+2] = 0.0f; out[4*p+3] = 0.0f;
                out[4*N_POST + p] = 0.0f;
            }
        }
    }
}

// ---------------- launch ------------------------------------------------------
extern "C" void kernel_launch(void* const* d_in, const int* in_sizes, int n_in,
                              void* d_out, int out_size, void* d_ws, size_t ws_size,
                              hipStream_t stream) {
    const float* anch = (const float*)d_in[0];   // (A,4)
    const float* cls  = (const float*)d_in[1];   // (1,A,2)
    const float* pred = (const float*)d_in[2];   // (1,A,4)
    float* out = (float*)d_out;                  // 8000 rois + 2000 kept

    char* ws = (char*)d_ws;
    float4*             roi    = (float4*)(ws + 0);                   // 298,800
    unsigned long long* key    = (unsigned long long*)(ws + 299008);  // 149,400
    unsigned*           phist  = (unsigned*)(ws + 448512);            // 311,296 (19*16KB)
    unsigned*           gcnt   = (unsigned*)(ws + 759808);            //  16,384
    unsigned long long* bkey   = (unsigned long long*)(ws + 776192);  // 149,400
    float4*             sboxes = (float4*)(ws + 925696);              // 192,000
    float*              sareas = (float*)(ws + 1117696);              //  48,000
    unsigned*           mark   = (unsigned*)(ws + 1165696);           //  48,000
    unsigned*           sync   = (unsigned*)(ws + 1213696);           //     256

    decode_kernel<<<NB0, 1024, 0, stream>>>(anch, cls, pred, roi, key, phist, gcnt, sync);
    main_kernel<<<NB1, 1024, 0, stream>>>(key, phist, gcnt, bkey, roi,
                                          sboxes, sareas, mark, sync, out);
}

// Round 11
// 94.628 us; speedup vs baseline: 1.8774x; 1.0909x over previous
//
#include <hip/hip_runtime.h>
#include <math.h>

#define A_TOT   18675      // 83*25*9
#define N_PRE   12000
#define N_POST  2000
#define IMG_X   1333.0f
#define IMG_Y   402.0f
#define MIN_SZ  16.0f
#define NMS_T   0.7f
#define NBUCK   4096       // top 12 bits of descending-order key
#define NB0     19         // decode blocks (19*1024 >= A_TOT)
#define NB1     256        // main kernel blocks (1 block/CU -> co-resident)
#define NW1     (NB1*16)   // main kernel waves (4096)

// ---------------- D0: init + decode -> roi, key, partial hists ---------------
__global__ __launch_bounds__(1024)
void decode_kernel(const float* __restrict__ anch,
                   const float* __restrict__ cls,
                   const float* __restrict__ pred,
                   float4* __restrict__ roi,
                   unsigned long long* __restrict__ key,
                   unsigned* __restrict__ phist,
                   unsigned* __restrict__ gcnt,
                   unsigned* __restrict__ sync) {
    __shared__ unsigned lh[NBUCK];
    const int t   = threadIdx.x;
    const int blk = blockIdx.x;
    const int g   = blk * 1024 + t;

#pragma unroll
    for (int e = 0; e < 4; ++e) lh[t + e * 1024] = 0u;
    if (g < NBUCK) gcnt[g] = 0u;
    if (g == NBUCK) { sync[0] = 0u; sync[32] = 0u; }   // bar, done
    __syncthreads();

    if (g < A_TOT) {
        float ax1 = anch[4*g+0], ay1 = anch[4*g+1], ax2 = anch[4*g+2], ay2 = anch[4*g+3];
        float h_a  = __fsub_rn(ay2, ay1);
        float w_a  = __fsub_rn(ax2, ax1);
        float cy_a = __fadd_rn(ay1, __fmul_rn(0.5f, h_a));
        float cx_a = __fadd_rn(ax1, __fmul_rn(0.5f, w_a));

        float dx = pred[4*g+0], dy = pred[4*g+1], dw = pred[4*g+2], dh = pred[4*g+3];

        float cy = __fadd_rn(__fmul_rn(dy, h_a), cy_a);
        float cx = __fadd_rn(__fmul_rn(dx, w_a), cx_a);
        float h  = __fmul_rn(expf(dh), h_a);
        float w  = __fmul_rn(expf(dw), w_a);

        float hw = __fmul_rn(0.5f, w);
        float hh = __fmul_rn(0.5f, h);
        float x1 = fminf(fmaxf(__fsub_rn(cx, hw), 0.0f), IMG_X);
        float x2 = fminf(fmaxf(__fadd_rn(cx, hw), 0.0f), IMG_X);
        float y1 = fminf(fmaxf(__fsub_rn(cy, hh), 0.0f), IMG_Y);
        float y2 = fminf(fmaxf(__fadd_rn(cy, hh), 0.0f), IMG_Y);

        bool valid = (__fsub_rn(y2, y1) >= MIN_SZ) && (__fsub_rn(x2, x1) >= MIN_SZ);

        roi[g] = make_float4(x1, y1, x2, y2);

        float s = valid ? cls[2*g+1] : -INFINITY;
        unsigned ub   = __float_as_uint(s);
        unsigned mask = ((unsigned)((int)ub >> 31)) | 0x80000000u;
        unsigned ord  = ub ^ mask;          // ascending float order
        unsigned kd   = ~ord;               // descending float order
        key[g] = ((unsigned long long)kd << 32) | (unsigned)g;
        atomicAdd(&lh[kd >> 20], 1u);
    }
    __syncthreads();

    ((uint4*)phist)[blk * 1024 + t] =
        make_uint4(lh[4*t+0], lh[4*t+1], lh[4*t+2], lh[4*t+3]);
}

// ---------------- hand-rolled grid barrier (device-scope) --------------------
__device__ __forceinline__ void gbar(unsigned* bar, unsigned target) {
    __syncthreads();
    if (threadIdx.x == 0) {
        __threadfence();                 // release prior writes to device scope
        atomicAdd(bar, 1u);
        long guard = 0;
        while (atomicAdd(bar, 0u) < target) {
            __builtin_amdgcn_s_sleep(4);
            if (++guard > (1L << 26)) break;   // hang guard only
        }
        __threadfence();                 // acquire
    }
    __syncthreads();
}

__device__ __forceinline__ float box_area(float4 b) {
    return __fmul_rn(__fadd_rn(__fsub_rn(b.z, b.x), 1.0f),
                     __fadd_rn(__fsub_rn(b.w, b.y), 1.0f));
}

// ---------------- D1: scan+scatter | rank | nms | last-block output ----------
__global__ __launch_bounds__(1024)
void main_kernel(const unsigned long long* __restrict__ key,
                 const unsigned* __restrict__ phist,
                 unsigned* __restrict__ gcnt,
                 unsigned long long* __restrict__ bkey,
                 const float4* __restrict__ roi,
                 float4* __restrict__ sboxes,
                 unsigned* __restrict__ mark,
                 unsigned* __restrict__ sync,
                 float* __restrict__ out) {
    __shared__ unsigned bs[NBUCK];
    __shared__ unsigned lcnt[NBUCK];
    __shared__ unsigned wsum[16];
    __shared__ int osum[16];
    __shared__ int ototal;
    __shared__ int sflag;

    const int t    = threadIdx.x;
    const int blk  = blockIdx.x;
    const int lane = t & 63;
    const int wv   = t >> 6;
    const int gw   = blk * 16 + wv;

    // ----- phase A: redundant per-block exclusive scan of summed hists -----
    {
        unsigned c0 = 0, c1 = 0, c2 = 0, c3 = 0;
#pragma unroll
        for (int k = 0; k < NB0; ++k) {
            uint4 v = ((const uint4*)phist)[k * 1024 + t];
            c0 += v.x; c1 += v.y; c2 += v.z; c3 += v.w;
        }
        unsigned mysum = c0 + c1 + c2 + c3;
        unsigned incl = mysum;
#pragma unroll
        for (int off = 1; off < 64; off <<= 1) {
            unsigned x = __shfl_up(incl, off, 64);
            if (lane >= off) incl += x;
        }
        if (lane == 63) wsum[wv] = incl;
        __syncthreads();
        if (t == 0) {
            unsigned run = 0;
            for (int k = 0; k < 16; ++k) { unsigned x = wsum[k]; wsum[k] = run; run += x; }
        }
        __syncthreads();
        unsigned base = wsum[wv] + (incl - mysum);
        bs[4*t+0] = base;
        bs[4*t+1] = base + c0;
        bs[4*t+2] = base + c0 + c1;
        bs[4*t+3] = base + c0 + c1 + c2;
        lcnt[4*t+0] = c0; lcnt[4*t+1] = c1; lcnt[4*t+2] = c2; lcnt[4*t+3] = c3;
        __syncthreads();
    }

    // ----- phase B: bucket scatter (blocks 0..18 carry the elements) -----
    {
        int g = blk * 1024 + t;
        if (g < A_TOT) {
            unsigned long long Ki = key[g];
            unsigned b = (unsigned)(Ki >> 52);
            unsigned pos = bs[b] + atomicAdd(&gcnt[b], 1u);
            bkey[pos] = Ki;
        }
    }
    gbar(sync, NB1);

    // ----- phase C: wave-ballot exact rank + scatter to sorted boxes -----
    for (int p = gw; p < A_TOT; p += NW1) {
        unsigned long long Ki = bkey[p];
        unsigned b = (unsigned)(Ki >> 52);
        unsigned start = bs[b];
        if (start >= N_PRE) continue;        // whole bucket past top-N_PRE
        unsigned cnt = lcnt[b];
        unsigned r = start;
        if (cnt > 1) {
            for (unsigned m = 0; m < cnt; m += 64) {
                unsigned mm = m + lane;
                bool lt = (mm < cnt) && (bkey[start + mm] < Ki);
                r += (unsigned)__popcll(__ballot(lt));
            }
        }
        if (lane == 0 && r < N_PRE) {
            sboxes[r] = roi[(unsigned)Ki];
        }
    }
    gbar(sync, 2u * NB1);

    // ----- phase D: DIAGONAL pair-overlap marking (the reference's predicate) --
    // mark[i] = OR over z in [0, N_PRE-1-i) of IoU(b[z], b[z+i+1]) >= 0.7
    for (int i = gw; i < N_PRE; i += NW1) {
        const int npairs = N_PRE - 1 - i;
        const int rounds = (npairs + 63) >> 6;
        bool found = false;
        if (rounds > 0) {
            float4 bz = sboxes[lane];                 // prefetch round 0: z
            float4 bo = sboxes[i + 1 + lane];         //                  z+i+1
            for (int rr = 0; rr < rounds; ++rr) {
                float4 cz = bz, co = bo;
                if (rr + 1 < rounds) {                // prefetch next round
                    int nb = (rr + 1) << 6;
                    bz = sboxes[nb + lane];
                    bo = sboxes[nb + i + 1 + lane];
                }
                int z = (rr << 6) + lane;
                bool over = false;
                if (z < npairs) {
                    float xx1 = fmaxf(cz.x, co.x);
                    float yy1 = fmaxf(cz.y, co.y);
                    float xx2 = fminf(cz.z, co.z);
                    float yy2 = fminf(cz.w, co.w);
                    float w = fmaxf(0.0f, __fadd_rn(__fsub_rn(xx2, xx1), 1.0f));
                    float h = fmaxf(0.0f, __fadd_rn(__fsub_rn(yy2, yy1), 1.0f));
                    float inter = __fmul_rn(w, h);
                    float az = box_area(cz);
                    float ao = box_area(co);
                    float denom = __fsub_rn(__fadd_rn(az, ao), inter);
                    float ovr   = __fdiv_rn(inter, denom);
                    over = (ovr >= NMS_T);
                }
                if (__any(over)) { found = true; break; }
            }
        }
        if (lane == 0) mark[i] = found ? 1u : 0u;
    }

    // ----- phase E: last block to finish performs the output -----
    __syncthreads();
    if (t == 0) {
        __threadfence();
        unsigned old = atomicAdd(&sync[32], 1u);
        sflag = (old == NB1 - 1) ? 1 : 0;
    }
    __syncthreads();
    if (!sflag) return;
    __threadfence();

    {
        const int E = 12;                 // 1024*12 = 12288 >= 12000
        const int i0 = t * E;
        bool keep[E];
        int cnt = 0;
#pragma unroll
        for (int e = 0; e < E; ++e) {
            int i = i0 + e;
            bool k = (i < N_PRE) && (mark[i] == 0u);
            keep[e] = k;
            cnt += k ? 1 : 0;
        }
        int incl = cnt;
#pragma unroll
        for (int off = 1; off < 64; off <<= 1) {
            int x = __shfl_up(incl, off, 64);
            if (lane >= off) incl += x;
        }
        if (lane == 63) osum[wv] = incl;
        __syncthreads();
        if (t == 0) {
            int run = 0;
            for (int k = 0; k < 16; ++k) { int x = osum[k]; osum[k] = run; run += x; }
            ototal = run;
        }
        __syncthreads();

        int pos = osum[wv] + (incl - cnt);
#pragma unroll
        for (int e = 0; e < E; ++e) {
            if (keep[e] && pos < N_POST) {
                float4 b4 = sboxes[i0 + e];
                out[4*pos+0] = b4.x;
                out[4*pos+1] = b4.y;
                out[4*pos+2] = b4.z;
                out[4*pos+3] = b4.w;
                out[4*N_POST + pos] = 1.0f;
            }
            pos += keep[e] ? 1 : 0;
        }
        const int total = ototal;
        for (int p = t; p < N_POST; p += 1024) {
            if (p >= total) {
                out[4*p+0] = 0.0f; out[4*p+1] = 0.0f;
                out[4*p+2] = 0.0f; out[4*p+3] = 0.0f;
                out[4*N_POST + p] = 0.0f;
            }
        }
    }
}

// ---------------- launch ------------------------------------------------------
extern "C" void kernel_launch(void* const* d_in, const int* in_sizes, int n_in,
                              void* d_out, int out_size, void* d_ws, size_t ws_size,
                              hipStream_t stream) {
    const float* anch = (const float*)d_in[0];   // (A,4)
    const float* cls  = (const float*)d_in[1];   // (1,A,2)
    const float* pred = (const float*)d_in[2];   // (1,A,4)
    float* out = (float*)d_out;                  // 8000 rois + 2000 kept

    char* ws = (char*)d_ws;
    float4*             roi    = (float4*)(ws + 0);                   // 298,800
    unsigned long long* key    = (unsigned long long*)(ws + 299008);  // 149,400
    unsigned*           phist  = (unsigned*)(ws + 448512);            // 311,296 (19*16KB)
    unsigned*           gcnt   = (unsigned*)(ws + 759808);            //  16,384
    unsigned long long* bkey   = (unsigned long long*)(ws + 776192);  // 149,400
    float4*             sboxes = (float4*)(ws + 925696);              // 192,000
    unsigned*           mark   = (unsigned*)(ws + 1117696);           //  48,000
    unsigned*           sync   = (unsigned*)(ws + 1165696);           //     256

    decode_kernel<<<NB0, 1024, 0, stream>>>(anch, cls, pred, roi, key, phist, gcnt, sync);
    main_kernel<<<NB1, 1024, 0, stream>>>(key, phist, gcnt, bkey, roi,
                                          sboxes, mark, sync, out);
}